// Round 2
// baseline (5975.829 us; speedup 1.0000x reference)
//
#include <hip/hip_runtime.h>
#include <cstddef>

#define BB 8
#define NN 1024
#define CIN 40
#define CH 64
#define CC 128
#define COUT 9
#define KS 9
#define NL 10
#define HSTEP 0.1f

// ---------------- helpers ----------------
__device__ __forceinline__ float blockSum(float v, float* red) {
    int tid = threadIdx.x;
    red[tid] = v;
    __syncthreads();
    for (int s = 128; s > 0; s >>= 1) {
        if (tid < s) red[tid] += red[tid + s];
        __syncthreads();
    }
    float r = red[0];
    __syncthreads();
    return r;
}

// ---------------- weight re-layout ----------------
// Win layout: [l][br][o(CC)][i(CH)][k]
// KerC : [l][br][i][k][o]   (conv1: float4 over o)
// KerT2: [l][br][o][k][i]   (conv1T: float4 over i)
__global__ __launch_bounds__(256) void k_prep_w(const float* __restrict__ Win,
                                                float* __restrict__ KerC,
                                                float* __restrict__ KerT2) {
    int idx = blockIdx.x * 256 + threadIdx.x;
    const int total = NL * 2 * CC * CH * KS;
    if (idx >= total) return;
    int k = idx % KS;
    int t = idx / KS;
    int i = t % CH;  t /= CH;
    int o = t % CC;  t /= CC;
    int lb = t;
    float v = Win[idx];
    KerC [((size_t)(lb * CH + i) * KS + k) * CC + o] = v;
    KerT2[((size_t)(lb * CC + o) * KS + k) * CH + i] = v;
}

// ---------------- open: Z = Kopen @ Zin * mask ----------------
__global__ __launch_bounds__(256) void k_open(const float* __restrict__ Zin,
                                              const float* __restrict__ mask,
                                              const float* __restrict__ Kop,
                                              float* __restrict__ Zcur) {
    int n = blockIdx.x * 256 + threadIdx.x;
    int c = blockIdx.y, b = blockIdx.z;
    float acc = 0.f;
    for (int i = 0; i < CIN; ++i)
        acc += Kop[c * CIN + i] * Zin[((size_t)b * CIN + i) * NN + n];
    Zcur[((size_t)b * CH + c) * NN + n] = acc * mask[b * NN + n];
}

// ---------------- Za: centered+normalized channels + pos, then mean-centered ----------------
__global__ __launch_bounds__(256) void k_za(const float* __restrict__ Zcur,
                                            const float* __restrict__ mask,
                                            float* __restrict__ Za) {
    __shared__ float red[256];
    int c = blockIdx.x;  // 0..64
    int b = blockIdx.y;
    int tid = threadIdx.x;
    const float* m = mask + b * NN;
    float x[4], mv[4];
    if (c < CH) {
        const float* src = Zcur + ((size_t)b * CH + c) * NN;
#pragma unroll
        for (int j = 0; j < 4; ++j) { int n = tid * 4 + j; x[j] = src[n]; mv[j] = m[n]; }
    } else {
#pragma unroll
        for (int j = 0; j < 4; ++j) { int n = tid * 4 + j; mv[j] = m[n]; x[j] = 0.5f * ((float)n / 1023.f) * mv[j]; }
    }
    float sm = 0.f, sxm = 0.f;
#pragma unroll
    for (int j = 0; j < 4; ++j) { sm += mv[j]; sxm += x[j] * mv[j]; }
    float msum = blockSum(sm, red);
    float xm = blockSum(sxm, red);
    if (c < CH) {
        float mean = xm / msum;
        float ss = 0.f;
#pragma unroll
        for (int j = 0; j < 4; ++j) { x[j] -= mean * mv[j]; ss += x[j] * x[j]; }
        ss = blockSum(ss, red);
        float sc = rsqrtf(ss / msum + 1e-4f);
#pragma unroll
        for (int j = 0; j < 4; ++j) x[j] *= sc;
    }
    float ps = 0.f;
#pragma unroll
    for (int j = 0; j < 4; ++j) ps += x[j];
    float pm = blockSum(ps, red) / (float)NN;
    float* dst = Za + ((size_t)b * 65 + c) * NN;
#pragma unroll
    for (int j = 0; j < 4; ++j) dst[tid * 4 + j] = x[j] - pm;
}

// ---------------- n2 over the 65 centered channels ----------------
__global__ __launch_bounds__(256) void k_n2g(const float* __restrict__ Za, float* __restrict__ n2g) {
    int n = blockIdx.x * 256 + threadIdx.x;
    int b = blockIdx.y;
    float s = 0.f;
    for (int c = 0; c < 65; ++c) { float v = Za[((size_t)b * 65 + c) * NN + n]; s += v * v; }
    n2g[b * NN + n] = s;
}

// ---------------- Gram + W = exp(-dist*mm)*mm ----------------
__global__ __launch_bounds__(256) void k_gramW(const float* __restrict__ Za,
                                               const float* __restrict__ n2g,
                                               const float* __restrict__ mask,
                                               float* __restrict__ Wg) {
    __shared__ float As[65][64];
    __shared__ float Bs2[65][64];
    int i0 = blockIdx.x * 64, j0 = blockIdx.y * 64, b = blockIdx.z;
    int tid = threadIdx.x;
    for (int e = tid; e < 65 * 64; e += 256) {
        int c = e >> 6, t = e & 63;
        const float* src = Za + ((size_t)b * 65 + c) * NN;
        As[c][t] = src[i0 + t];
        Bs2[c][t] = src[j0 + t];
    }
    __syncthreads();
    int tx = tid & 15, ty = tid >> 4;
    float acc[4][4] = {};
    for (int c = 0; c < 65; ++c) {
        float a[4];
#pragma unroll
        for (int q = 0; q < 4; ++q) a[q] = As[c][ty * 4 + q];
        float bv[4];
        *reinterpret_cast<float4*>(bv) = *reinterpret_cast<const float4*>(&Bs2[c][tx * 4]);
#pragma unroll
        for (int q = 0; q < 4; ++q)
#pragma unroll
            for (int r = 0; r < 4; ++r) acc[q][r] += a[q] * bv[r];
    }
    const float* m = mask + b * NN;
    for (int q = 0; q < 4; ++q) {
        int i = i0 + ty * 4 + q;
        float n2i = n2g[b * NN + i], mi = m[i];
        float res[4];
#pragma unroll
        for (int r = 0; r < 4; ++r) {
            int j = j0 + tx * 4 + r;
            float D = n2i + n2g[b * NN + j] - 2.f * acc[q][r];
            D *= (3.f / 65.f);
            D = fmaxf(D, 0.f);
            float dist = (D > 0.f) ? sqrtf(D) : 0.f;
            float mmv = mi * m[j];
            res[r] = expf(-dist * mmv) * mmv;
        }
        *reinterpret_cast<float4*>(&Wg[((size_t)b * NN + i) * NN + j0 + tx * 4]) =
            *reinterpret_cast<float4*>(res);
    }
}

// ---------------- Wsum (column sums == row sums, W symmetric) ----------------
__global__ __launch_bounds__(256) void k_wsum(const float* __restrict__ Wg, float* __restrict__ Wsum) {
    int j = blockIdx.x * 256 + threadIdx.x;
    int b = blockIdx.y;
    float s = 0.f;
#pragma unroll 8
    for (int i = 0; i < NN; ++i) s += Wg[((size_t)b * NN + i) * NN + j];
    Wsum[b * NN + j] = s;
}

// ---------------- conv1: out[b,o,n] = sum_{i,k} Ker[o,i,k]*(Z[b,i,n+k-4]+bias[i]) ----------------
__global__ __launch_bounds__(256) void k_conv1(const float* __restrict__ Zin,
                                               const float* __restrict__ KerC_lb,
                                               const float* __restrict__ bias,
                                               const float* __restrict__ mask,
                                               float* __restrict__ Out, int maskFlag) {
    __shared__ __align__(16) float xs[CH][136];
    int n0 = blockIdx.x * 128;
    int og = blockIdx.y * 32;
    int b = blockIdx.z;
    int tid = threadIdx.x;
    for (int e = tid; e < CH * 136; e += 256) {
        int i = e / 136, t = e - i * 136;
        int n = n0 + t - 4;
        xs[i][t] = (n >= 0 && n < NN) ? (Zin[((size_t)b * CH + i) * NN + n] + bias[i]) : 0.f;
    }
    __syncthreads();
    int nl = tid & 31, ot = tid >> 5;  // o = og+ot*4+q, n = n0+nl*4+j
    float acc[4][4] = {};
    for (int i = 0; i < CH; ++i) {
        float xr[12];
#pragma unroll
        for (int t = 0; t < 3; ++t)
            reinterpret_cast<float4*>(xr)[t] = reinterpret_cast<const float4*>(&xs[i][nl * 4])[t];
#pragma unroll
        for (int k = 0; k < KS; ++k) {
            float wv[4];
            *reinterpret_cast<float4*>(wv) =
                *reinterpret_cast<const float4*>(&KerC_lb[(size_t)(i * KS + k) * CC + og + ot * 4]);
#pragma unroll
            for (int q = 0; q < 4; ++q)
#pragma unroll
                for (int j = 0; j < 4; ++j) acc[q][j] += wv[q] * xr[j + k];
        }
    }
    int nbase = n0 + nl * 4;
#pragma unroll
    for (int q = 0; q < 4; ++q) {
        int o = og + ot * 4 + q;
        float res[4];
        if (maskFlag) {
#pragma unroll
            for (int j = 0; j < 4; ++j) res[j] = acc[q][j] * mask[b * NN + nbase + j];
        } else {
#pragma unroll
            for (int j = 0; j < 4; ++j) res[j] = acc[q][j];
        }
        *reinterpret_cast<float4*>(&Out[((size_t)b * CC + o) * NN + nbase]) =
            *reinterpret_cast<float4*>(res);
    }
}

// ---------------- conv1T: out[b,i,n] = sum_{o,k} Ker[o,i,k]*A[b,o,n+4-k] ----------------
__global__ __launch_bounds__(256) void k_conv1T(const float* __restrict__ Ain,
                                                const float* __restrict__ KerT_lb,
                                                float* __restrict__ Out) {
    __shared__ __align__(16) float xs[CC][72];
    int n0 = blockIdx.x * 64;
    int ig = blockIdx.y * 32;
    int b = blockIdx.z;
    int tid = threadIdx.x;
    for (int e = tid; e < CC * 72; e += 256) {
        int o = e / 72, t = e - o * 72;
        int n = n0 + t - 4;
        xs[o][t] = (n >= 0 && n < NN) ? Ain[((size_t)b * CC + o) * NN + n] : 0.f;
    }
    __syncthreads();
    int nl = tid & 31, it = tid >> 5;  // i = ig+it*4+q, n = n0+nl*2+j
    float acc[4][2] = {};
    for (int o = 0; o < CC; ++o) {
        float xr[10];
#pragma unroll
        for (int t = 0; t < 5; ++t)
            reinterpret_cast<float2*>(xr)[t] = reinterpret_cast<const float2*>(&xs[o][nl * 2])[t];
#pragma unroll
        for (int k = 0; k < KS; ++k) {
            float wv[4];
            *reinterpret_cast<float4*>(wv) =
                *reinterpret_cast<const float4*>(&KerT_lb[(size_t)(o * KS + k) * CH + ig + it * 4]);
#pragma unroll
            for (int q = 0; q < 4; ++q) {
                acc[q][0] += wv[q] * xr[8 - k];
                acc[q][1] += wv[q] * xr[9 - k];
            }
        }
    }
#pragma unroll
    for (int q = 0; q < 4; ++q) {
        int i = ig + it * 4 + q;
        float2 res;
        res.x = acc[q][0];
        res.y = acc[q][1];
        *reinterpret_cast<float2*>(&Out[((size_t)b * CH + i) * NN + n0 + nl * 2]) = res;
    }
}

// ---------------- X @ L (L = diag(Wsum) - W) with epilogues ----------------
// Block computes 32*TM channels x 32 n. 256 threads: tx=n-group (8x4), ty=c-group (32xTM).
// mode 0: Out = (X@L)*mask
// mode 1: Out (=Zcur) = Zcur - H*mask*(T0 + X@L)
template <int TM>
__global__ __launch_bounds__(256) void k_matL(const float* __restrict__ X,
                                              const float* __restrict__ Wg,
                                              const float* __restrict__ Wsum,
                                              const float* __restrict__ mask,
                                              const float* __restrict__ T0,
                                              float* __restrict__ Out, int rows, int mode) {
    __shared__ float Xs[32 * TM][33];
    __shared__ float Ws[32][32];
    int n0 = blockIdx.x * 32;
    int c0 = blockIdx.y * 32 * TM;
    int b = blockIdx.z;
    int tid = threadIdx.x;
    int tx = tid & 7, ty = tid >> 3;  // n = n0+tx*4+r, c = c0+ty*TM+q
    const float* Xb = X + (size_t)b * rows * NN;
    const float* Wb = Wg + (size_t)b * NN * NN;
    float acc[TM][4] = {};
    for (int m0 = 0; m0 < NN; m0 += 32) {
        for (int e = tid; e < 32 * TM * 32; e += 256) {
            int cc = e >> 5, kk = e & 31;
            Xs[cc][kk] = Xb[(size_t)(c0 + cc) * NN + m0 + kk];
        }
        for (int e = tid; e < 1024; e += 256) {
            int kk = e >> 5, nn = e & 31;
            Ws[kk][nn] = Wb[(size_t)(m0 + kk) * NN + n0 + nn];
        }
        __syncthreads();
#pragma unroll 8
        for (int kk = 0; kk < 32; ++kk) {
            float a[TM];
#pragma unroll
            for (int q = 0; q < TM; ++q) a[q] = Xs[ty * TM + q][kk];
            float bv[4];
            *reinterpret_cast<float4*>(bv) = *reinterpret_cast<const float4*>(&Ws[kk][tx * 4]);
#pragma unroll
            for (int q = 0; q < TM; ++q)
#pragma unroll
                for (int r = 0; r < 4; ++r) acc[q][r] += a[q] * bv[r];
        }
        __syncthreads();
    }
    for (int q = 0; q < TM; ++q) {
        int c = c0 + ty * TM + q;
        float res[4];
#pragma unroll
        for (int r = 0; r < 4; ++r) {
            int n = n0 + tx * 4 + r;
            float y = Xb[(size_t)c * NN + n] * Wsum[b * NN + n] - acc[q][r];
            if (mode == 0) {
                res[r] = y * mask[b * NN + n];
            } else {
                float t0v = T0[((size_t)b * rows + c) * NN + n];
                res[r] = Out[((size_t)b * rows + c) * NN + n] - HSTEP * mask[b * NN + n] * (t0v + y);
            }
        }
        *reinterpret_cast<float4*>(&Out[((size_t)b * rows + c) * NN + n0 + tx * 4]) =
            *reinterpret_cast<float4*>(res);
    }
}

// ---------------- masked row mean per (b,c) ----------------
__global__ __launch_bounds__(256) void k_rowmean(const float* __restrict__ X,
                                                 const float* __restrict__ mask,
                                                 float* __restrict__ meanA, int rows) {
    __shared__ float red[256];
    int c = blockIdx.x, b = blockIdx.y, tid = threadIdx.x;
    const float* src = X + ((size_t)b * rows + c) * NN;
    const float* m = mask + b * NN;
    float s = 0.f, sm = 0.f;
    for (int n = tid; n < NN; n += 256) { float mv = m[n]; s += src[n] * mv; sm += mv; }
    float ts = blockSum(s, red);
    float tm = blockSum(sm, red);
    if (tid == 0) meanA[b * rows + c] = ts / tm;
}

// ---------------- per-column: subtract mean, mask, channel-normalize, relu ----------------
__global__ __launch_bounds__(256) void k_colnorm(float* __restrict__ X,
                                                 const float* __restrict__ mask,
                                                 const float* __restrict__ meanA, int rows) {
    int n = blockIdx.x * 256 + threadIdx.x;
    int b = blockIdx.y;
    float mv = mask[b * NN + n];
    float ss = 0.f;
    for (int c = 0; c < rows; ++c) {
        float v = (X[((size_t)b * rows + c) * NN + n] - meanA[b * rows + c]) * mv;
        ss += v * v;
    }
    float inv = rsqrtf(ss + 0.001f);
    for (int c = 0; c < rows; ++c) {
        float v = (X[((size_t)b * rows + c) * NN + n] - meanA[b * rows + c]) * mv;
        X[((size_t)b * rows + c) * NN + n] = fmaxf(v * inv, 0.f);
    }
}

// ---------------- close: Zout = Kclose @ Z * mask ----------------
__global__ __launch_bounds__(256) void k_close(const float* __restrict__ Zcur,
                                               const float* __restrict__ Kcl,
                                               const float* __restrict__ mask,
                                               float* __restrict__ Zout) {
    int n = blockIdx.x * 256 + threadIdx.x;
    int b = blockIdx.y;
    float acc[COUT] = {};
    for (int c = 0; c < CH; ++c) {
        float zv = Zcur[((size_t)b * CH + c) * NN + n];
#pragma unroll
        for (int o = 0; o < COUT; ++o) acc[o] += Kcl[o * CH + c] * zv;
    }
    float mv = mask[b * NN + n];
#pragma unroll
    for (int o = 0; o < COUT; ++o) Zout[((size_t)b * COUT + o) * NN + n] = acc[o] * mv;
}

// ---------------- center final channels (plain mean) ----------------
__global__ __launch_bounds__(256) void k_center3(const float* __restrict__ Zout, float* __restrict__ Zc3) {
    __shared__ float red[256];
    int c = blockIdx.x, b = blockIdx.y, tid = threadIdx.x;
    const float* src = Zout + ((size_t)b * COUT + c) * NN;
    float s = 0.f;
    for (int n = tid; n < NN; n += 256) s += src[n];
    float mean = blockSum(s, red) / (float)NN;
    float* dst = Zc3 + ((size_t)b * COUT + c) * NN;
    for (int n = tid; n < NN; n += 256) dst[n] = src[n] - mean;
}

__global__ __launch_bounds__(256) void k_n23(const float* __restrict__ Zc3, float* __restrict__ n23) {
    int n = blockIdx.x * 256 + threadIdx.x;
    int g = blockIdx.y, b = blockIdx.z;
    float s = 0.f;
#pragma unroll
    for (int c = 0; c < 3; ++c) { float v = Zc3[((size_t)b * COUT + g * 3 + c) * NN + n]; s += v * v; }
    n23[((size_t)b * 3 + g) * NN + n] = s;
}

// ---------------- final pairwise distances ----------------
__global__ __launch_bounds__(256) void k_dist(const float* __restrict__ Zc3,
                                              const float* __restrict__ n23,
                                              float* __restrict__ dout) {
    __shared__ float Ai[3][64], Aj[3][64], ni[64], nj[64];
    int bg = blockIdx.z;
    int b = bg / 3, g = bg - 3 * b;
    int i0 = blockIdx.x * 64, j0 = blockIdx.y * 64;
    int tid = threadIdx.x;
    if (tid < 64) ni[tid] = n23[((size_t)b * 3 + g) * NN + i0 + tid];
    else if (tid < 128) { int t = tid - 64; nj[t] = n23[((size_t)b * 3 + g) * NN + j0 + t]; }
    for (int e = tid; e < 192; e += 256) {
        int c = e / 64, t = e - c * 64;
        Ai[c][t] = Zc3[((size_t)b * COUT + g * 3 + c) * NN + i0 + t];
    }
    for (int e = tid; e < 192; e += 256) {
        int c = e / 64, t = e - c * 64;
        Aj[c][t] = Zc3[((size_t)b * COUT + g * 3 + c) * NN + j0 + t];
    }
    __syncthreads();
    int tx = tid & 15, ty = tid >> 4;
    for (int q = 0; q < 4; ++q) {
        int i = ty * 4 + q;
        float a0 = Ai[0][i], a1 = Ai[1][i], a2 = Ai[2][i], n2i = ni[i];
        float res[4];
#pragma unroll
        for (int r = 0; r < 4; ++r) {
            int j = tx * 4 + r;
            float D = n2i + nj[j] - 2.f * (a0 * Aj[0][j] + a1 * Aj[1][j] + a2 * Aj[2][j]);
            D = fmaxf(D, 0.f);
            res[r] = (D > 0.f) ? sqrtf(D) : 0.f;
        }
        *reinterpret_cast<float4*>(&dout[(((size_t)b * 3 + g) * NN + i0 + i) * NN + j0 + tx * 4]) =
            *reinterpret_cast<float4*>(res);
    }
}

// ---------------- driver ----------------
extern "C" void kernel_launch(void* const* d_in, const int* in_sizes, int n_in,
                              void* d_out, int out_size, void* d_ws, size_t ws_size,
                              hipStream_t stream) {
    (void)in_sizes; (void)n_in; (void)out_size; (void)ws_size;
    const float* Zin  = (const float*)d_in[0];
    const float* mask = (const float*)d_in[1];
    const float* Kop  = (const float*)d_in[2];
    const float* Kcl  = (const float*)d_in[3];
    const float* Win  = (const float*)d_in[4];
    const float* Bias = (const float*)d_in[5];
    float* out = (float*)d_out;
    float* ws = (float*)d_ws;

    size_t off = 0;
    float* Zcur = ws + off;  off += (size_t)BB * CH * NN;
    float* C0   = ws + off;  off += (size_t)BB * CC * NN;
    float* C1   = ws + off;  off += (size_t)BB * CC * NN;
    float* A1   = ws + off;  off += (size_t)BB * CC * NN;
    float* T0   = ws + off;  off += (size_t)BB * CH * NN;
    float* T1p  = ws + off;  off += (size_t)BB * CH * NN;
    float* Za   = ws + off;  off += (size_t)BB * 65 * NN;
    float* n2g  = ws + off;  off += (size_t)BB * NN;
    float* Wg   = ws + off;  off += (size_t)BB * NN * NN;
    float* Wsum = ws + off;  off += (size_t)BB * NN;
    float* meanA= ws + off;  off += (size_t)BB * CC;
    float* KerC = ws + off;  off += (size_t)NL * 2 * CH * KS * CC;
    float* KerT2= ws + off;  off += (size_t)NL * 2 * CC * KS * CH;
    float* Zc3  = ws + off;  off += (size_t)BB * COUT * NN;
    float* n23  = ws + off;  off += (size_t)BB * 3 * NN;

    k_prep_w<<<dim3((NL * 2 * CC * CH * KS + 255) / 256), 256, 0, stream>>>(Win, KerC, KerT2);
    k_open<<<dim3(NN / 256, CH, BB), 256, 0, stream>>>(Zin, mask, Kop, Zcur);
    k_za<<<dim3(65, BB), 256, 0, stream>>>(Zcur, mask, Za);
    k_n2g<<<dim3(NN / 256, BB), 256, 0, stream>>>(Za, n2g);
    k_gramW<<<dim3(16, 16, BB), 256, 0, stream>>>(Za, n2g, mask, Wg);
    k_wsum<<<dim3(NN / 256, BB), 256, 0, stream>>>(Wg, Wsum);

    for (int l = 0; l < NL; ++l) {
        const float* KC0 = KerC + (size_t)(l * 2 + 0) * CH * KS * CC;
        const float* KC1 = KerC + (size_t)(l * 2 + 1) * CH * KS * CC;
        const float* KT0 = KerT2 + (size_t)(l * 2 + 0) * CC * KS * CH;
        const float* KT1 = KerT2 + (size_t)(l * 2 + 1) * CC * KS * CH;
        const float* b0 = Bias + (size_t)(l * 2 + 0) * CH;
        const float* b1 = Bias + (size_t)(l * 2 + 1) * CH;

        k_conv1<<<dim3(NN / 128, CC / 32, BB), 256, 0, stream>>>(Zcur, KC0, b0, mask, C0, 1);
        k_conv1<<<dim3(NN / 128, CC / 32, BB), 256, 0, stream>>>(Zcur, KC1, b1, mask, C1, 0);
        k_matL<4><<<dim3(NN / 32, CC / 128, BB), 256, 0, stream>>>(C1, Wg, Wsum, mask, nullptr, A1, CC, 0);
        k_rowmean<<<dim3(CC, BB), 256, 0, stream>>>(C0, mask, meanA, CC);
        k_colnorm<<<dim3(NN / 256, BB), 256, 0, stream>>>(C0, mask, meanA, CC);
        k_rowmean<<<dim3(CC, BB), 256, 0, stream>>>(A1, mask, meanA, CC);
        k_colnorm<<<dim3(NN / 256, BB), 256, 0, stream>>>(A1, mask, meanA, CC);
        k_conv1T<<<dim3(NN / 64, CH / 32, BB), 256, 0, stream>>>(C0, KT0, T0);
        k_conv1T<<<dim3(NN / 64, CH / 32, BB), 256, 0, stream>>>(A1, KT1, T1p);
        k_matL<2><<<dim3(NN / 32, CH / 64, BB), 256, 0, stream>>>(T1p, Wg, Wsum, mask, T0, Zcur, CH, 1);
    }

    float* Zout = out + (size_t)BB * 3 * NN * NN;
    k_close<<<dim3(NN / 256, BB), 256, 0, stream>>>(Zcur, Kcl, mask, Zout);
    k_center3<<<dim3(COUT, BB), 256, 0, stream>>>(Zout, Zc3);
    k_n23<<<dim3(NN / 256, 3, BB), 256, 0, stream>>>(Zc3, n23);
    k_dist<<<dim3(16, 16, 3 * BB), 256, 0, stream>>>(Zc3, n23, out);
}

// Round 3
// 3766.722 us; speedup vs baseline: 1.5865x; 1.5865x over previous
//
#include <hip/hip_runtime.h>
#include <cstddef>

#define BB 8
#define NN 1024
#define CIN 40
#define CH 64
#define CC 128
#define COUT 9
#define KS 9
#define NL 10
#define HSTEP 0.1f
#define SK 4   // split-K factor for matL

// ---------------- helpers ----------------
__device__ __forceinline__ float blockSum(float v, float* red) {
    int tid = threadIdx.x;
    red[tid] = v;
    __syncthreads();
    for (int s = 128; s > 0; s >>= 1) {
        if (tid < s) red[tid] += red[tid + s];
        __syncthreads();
    }
    float r = red[0];
    __syncthreads();
    return r;
}

// ---------------- weight re-layout ----------------
// Win layout: [l][br][o(CC)][i(CH)][k]
// KerC : [l][br][i][k][o]   (conv1: float4 over o)
// KerT2: [l][br][o][k][i]   (conv1T: float4 over i)
__global__ __launch_bounds__(256) void k_prep_w(const float* __restrict__ Win,
                                                float* __restrict__ KerC,
                                                float* __restrict__ KerT2) {
    int idx = blockIdx.x * 256 + threadIdx.x;
    const int total = NL * 2 * CC * CH * KS;
    if (idx >= total) return;
    int k = idx % KS;
    int t = idx / KS;
    int i = t % CH;  t /= CH;
    int o = t % CC;  t /= CC;
    int lb = t;
    float v = Win[idx];
    KerC [((size_t)(lb * CH + i) * KS + k) * CC + o] = v;
    KerT2[((size_t)(lb * CC + o) * KS + k) * CH + i] = v;
}

// bks[lb][o][k] = sum_i Win[lb][o][i][k] * Bias[lb][i]
__global__ __launch_bounds__(256) void k_prep_bks(const float* __restrict__ Win,
                                                  const float* __restrict__ Bias,
                                                  float* __restrict__ bks) {
    int idx = blockIdx.x * 256 + threadIdx.x;
    const int total = NL * 2 * CC * KS;
    if (idx >= total) return;
    int k = idx % KS;
    int t = idx / KS;
    int o = t % CC;
    int lb = t / CC;
    float s = 0.f;
    for (int i = 0; i < CH; ++i)
        s += Win[(((size_t)lb * CC + o) * CH + i) * KS + k] * Bias[lb * CH + i];
    bks[idx] = s;
}

// ---------------- open: Z = Kopen @ Zin * mask ----------------
__global__ __launch_bounds__(256) void k_open(const float* __restrict__ Zin,
                                              const float* __restrict__ mask,
                                              const float* __restrict__ Kop,
                                              float* __restrict__ Zcur) {
    int n = blockIdx.x * 256 + threadIdx.x;
    int c = blockIdx.y, b = blockIdx.z;
    float acc = 0.f;
    for (int i = 0; i < CIN; ++i)
        acc += Kop[c * CIN + i] * Zin[((size_t)b * CIN + i) * NN + n];
    Zcur[((size_t)b * CH + c) * NN + n] = acc * mask[b * NN + n];
}

// ---------------- Za: centered+normalized channels + pos, then mean-centered ----------------
__global__ __launch_bounds__(256) void k_za(const float* __restrict__ Zcur,
                                            const float* __restrict__ mask,
                                            float* __restrict__ Za) {
    __shared__ float red[256];
    int c = blockIdx.x;  // 0..64
    int b = blockIdx.y;
    int tid = threadIdx.x;
    const float* m = mask + b * NN;
    float x[4], mv[4];
    if (c < CH) {
        const float* src = Zcur + ((size_t)b * CH + c) * NN;
#pragma unroll
        for (int j = 0; j < 4; ++j) { int n = tid * 4 + j; x[j] = src[n]; mv[j] = m[n]; }
    } else {
#pragma unroll
        for (int j = 0; j < 4; ++j) { int n = tid * 4 + j; mv[j] = m[n]; x[j] = 0.5f * ((float)n / 1023.f) * mv[j]; }
    }
    float sm = 0.f, sxm = 0.f;
#pragma unroll
    for (int j = 0; j < 4; ++j) { sm += mv[j]; sxm += x[j] * mv[j]; }
    float msum = blockSum(sm, red);
    float xm = blockSum(sxm, red);
    if (c < CH) {
        float mean = xm / msum;
        float ss = 0.f;
#pragma unroll
        for (int j = 0; j < 4; ++j) { x[j] -= mean * mv[j]; ss += x[j] * x[j]; }
        ss = blockSum(ss, red);
        float sc = rsqrtf(ss / msum + 1e-4f);
#pragma unroll
        for (int j = 0; j < 4; ++j) x[j] *= sc;
    }
    float ps = 0.f;
#pragma unroll
    for (int j = 0; j < 4; ++j) ps += x[j];
    float pm = blockSum(ps, red) / (float)NN;
    float* dst = Za + ((size_t)b * 65 + c) * NN;
#pragma unroll
    for (int j = 0; j < 4; ++j) dst[tid * 4 + j] = x[j] - pm;
}

// ---------------- n2 over the 65 centered channels ----------------
__global__ __launch_bounds__(256) void k_n2g(const float* __restrict__ Za, float* __restrict__ n2g) {
    int n = blockIdx.x * 256 + threadIdx.x;
    int b = blockIdx.y;
    float s = 0.f;
    for (int c = 0; c < 65; ++c) { float v = Za[((size_t)b * 65 + c) * NN + n]; s += v * v; }
    n2g[b * NN + n] = s;
}

// ---------------- Gram + W = exp(-dist*mm)*mm ----------------
__global__ __launch_bounds__(256) void k_gramW(const float* __restrict__ Za,
                                               const float* __restrict__ n2g,
                                               const float* __restrict__ mask,
                                               float* __restrict__ Wg) {
    __shared__ float As[65][64];
    __shared__ float Bs2[65][64];
    int i0 = blockIdx.x * 64, j0 = blockIdx.y * 64, b = blockIdx.z;
    int tid = threadIdx.x;
    for (int e = tid; e < 65 * 64; e += 256) {
        int c = e >> 6, t = e & 63;
        const float* src = Za + ((size_t)b * 65 + c) * NN;
        As[c][t] = src[i0 + t];
        Bs2[c][t] = src[j0 + t];
    }
    __syncthreads();
    int tx = tid & 15, ty = tid >> 4;
    float acc[4][4] = {};
    for (int c = 0; c < 65; ++c) {
        float a[4];
#pragma unroll
        for (int q = 0; q < 4; ++q) a[q] = As[c][ty * 4 + q];
        float bv[4];
        *reinterpret_cast<float4*>(bv) = *reinterpret_cast<const float4*>(&Bs2[c][tx * 4]);
#pragma unroll
        for (int q = 0; q < 4; ++q)
#pragma unroll
            for (int r = 0; r < 4; ++r) acc[q][r] += a[q] * bv[r];
    }
    const float* m = mask + b * NN;
    for (int q = 0; q < 4; ++q) {
        int i = i0 + ty * 4 + q;
        float n2i = n2g[b * NN + i], mi = m[i];
        float res[4];
#pragma unroll
        for (int r = 0; r < 4; ++r) {
            int j = j0 + tx * 4 + r;
            float D = n2i + n2g[b * NN + j] - 2.f * acc[q][r];
            D *= (3.f / 65.f);
            D = fmaxf(D, 0.f);
            float dist = (D > 0.f) ? sqrtf(D) : 0.f;
            float mmv = mi * m[j];
            res[r] = expf(-dist * mmv) * mmv;
        }
        *reinterpret_cast<float4*>(&Wg[((size_t)b * NN + i) * NN + j0 + tx * 4]) =
            *reinterpret_cast<float4*>(res);
    }
}

// ---------------- Wsum ----------------
__global__ __launch_bounds__(256) void k_wsum(const float* __restrict__ Wg, float* __restrict__ Wsum) {
    int j = blockIdx.x * 256 + threadIdx.x;
    int b = blockIdx.y;
    float s = 0.f;
#pragma unroll 8
    for (int i = 0; i < NN; ++i) s += Wg[((size_t)b * NN + i) * NN + j];
    Wsum[b * NN + j] = s;
}

// ---------------- fused conv1 pair: computes C0 (masked, br=0) and C1 (br=1) ----------------
// bias folded analytically via bks[o][k] with boundary validity.
__global__ __launch_bounds__(256) void k_conv1f(const float* __restrict__ Zin,
                                                const float* __restrict__ KerC_l,  // [2][i][k][o]
                                                const float* __restrict__ bks_l,   // [2][o][k]
                                                const float* __restrict__ mask,
                                                float* __restrict__ C0,
                                                float* __restrict__ C1) {
    __shared__ __align__(16) float xs[CH][136];
    int n0 = blockIdx.x * 128;
    int og2 = blockIdx.y * 32;       // 0..255 across [C0's 128 | C1's 128]
    int b = blockIdx.z;
    int br = og2 >> 7;
    int og = og2 & 127;
    const float* K = KerC_l + (size_t)br * CH * KS * CC;
    const float* bks = bks_l + (size_t)br * CC * KS;
    int tid = threadIdx.x;
    for (int e = tid; e < CH * 136; e += 256) {
        int i = e / 136, t = e - i * 136;
        int n = n0 + t - 4;
        xs[i][t] = (n >= 0 && n < NN) ? Zin[((size_t)b * CH + i) * NN + n] : 0.f;
    }
    __syncthreads();
    int nl = tid & 31, ot = tid >> 5;  // o = og+ot*4+q, n = n0+nl*4+j
    float acc[4][4] = {};
    for (int i = 0; i < CH; ++i) {
        float xr[12];
#pragma unroll
        for (int t = 0; t < 3; ++t)
            reinterpret_cast<float4*>(xr)[t] = reinterpret_cast<const float4*>(&xs[i][nl * 4])[t];
#pragma unroll
        for (int k = 0; k < KS; ++k) {
            float wv[4];
            *reinterpret_cast<float4*>(wv) =
                *reinterpret_cast<const float4*>(&K[(size_t)(i * KS + k) * CC + og + ot * 4]);
#pragma unroll
            for (int q = 0; q < 4; ++q)
#pragma unroll
                for (int j = 0; j < 4; ++j) acc[q][j] += wv[q] * xr[j + k];
        }
    }
    int nbase = n0 + nl * 4;
    float* Out = br ? C1 : C0;
#pragma unroll
    for (int q = 0; q < 4; ++q) {
        int o = og + ot * 4 + q;
        const float* bo = bks + o * KS;
        float res[4];
#pragma unroll
        for (int j = 0; j < 4; ++j) {
            int n = nbase + j;
            float bias = 0.f;
#pragma unroll
            for (int k = 0; k < KS; ++k) {
                int nn = n + k - 4;
                if (nn >= 0 && nn < NN) bias += bo[k];
            }
            float v = acc[q][j] + bias;
            res[j] = br ? v : v * mask[b * NN + n];
        }
        *reinterpret_cast<float4*>(&Out[((size_t)b * CC + o) * NN + nbase]) =
            *reinterpret_cast<float4*>(res);
    }
}

// ---------------- conv1T: out[b,i,n] = sum_{o,k} Ker[o,i,k]*A[b,o,n+4-k] ----------------
__global__ __launch_bounds__(256) void k_conv1T(const float* __restrict__ Ain,
                                                const float* __restrict__ KerT_lb,
                                                float* __restrict__ Out) {
    __shared__ __align__(16) float xs[CC][72];
    int n0 = blockIdx.x * 64;
    int ig = blockIdx.y * 32;
    int b = blockIdx.z;
    int tid = threadIdx.x;
    for (int e = tid; e < CC * 72; e += 256) {
        int o = e / 72, t = e - o * 72;
        int n = n0 + t - 4;
        xs[o][t] = (n >= 0 && n < NN) ? Ain[((size_t)b * CC + o) * NN + n] : 0.f;
    }
    __syncthreads();
    int nl = tid & 31, it = tid >> 5;  // i = ig+it*4+q, n = n0+nl*2+j
    float acc[4][2] = {};
    for (int o = 0; o < CC; ++o) {
        float xr[10];
#pragma unroll
        for (int t = 0; t < 5; ++t)
            reinterpret_cast<float2*>(xr)[t] = reinterpret_cast<const float2*>(&xs[o][nl * 2])[t];
#pragma unroll
        for (int k = 0; k < KS; ++k) {
            float wv[4];
            *reinterpret_cast<float4*>(wv) =
                *reinterpret_cast<const float4*>(&KerT_lb[(size_t)(o * KS + k) * CH + ig + it * 4]);
#pragma unroll
            for (int q = 0; q < 4; ++q) {
                acc[q][0] += wv[q] * xr[8 - k];
                acc[q][1] += wv[q] * xr[9 - k];
            }
        }
    }
#pragma unroll
    for (int q = 0; q < 4; ++q) {
        int i = ig + it * 4 + q;
        float2 res;
        res.x = acc[q][0];
        res.y = acc[q][1];
        *reinterpret_cast<float2*>(&Out[((size_t)b * CH + i) * NN + n0 + nl * 2]) = res;
    }
}

// ---------------- split-K X@W partials ----------------
// grid (NN/32, SK, BB); block covers all rows (32*TM) x 32 n, K-chunk NN/SK.
template <int TM>
__global__ __launch_bounds__(256) void k_matL_part(const float* __restrict__ X,
                                                   const float* __restrict__ Wg,
                                                   float* __restrict__ Part, int rows) {
    __shared__ float Xs[32 * TM][33];
    __shared__ float Ws[32][32];
    int n0 = blockIdx.x * 32;
    int sk = blockIdx.y;
    int b = blockIdx.z;
    int tid = threadIdx.x;
    int tx = tid & 7, ty = tid >> 3;  // n = n0+tx*4+r, c = ty*TM+q
    const float* Xb = X + (size_t)b * rows * NN;
    const float* Wb = Wg + (size_t)b * NN * NN;
    float acc[TM][4] = {};
    int m_beg = sk * (NN / SK);
    for (int m0 = m_beg; m0 < m_beg + NN / SK; m0 += 32) {
        for (int e = tid; e < 32 * TM * 32; e += 256) {
            int cc = e >> 5, kk = e & 31;
            Xs[cc][kk] = Xb[(size_t)cc * NN + m0 + kk];
        }
        for (int e = tid; e < 1024; e += 256) {
            int kk = e >> 5, nn = e & 31;
            Ws[kk][nn] = Wb[(size_t)(m0 + kk) * NN + n0 + nn];
        }
        __syncthreads();
#pragma unroll 8
        for (int kk = 0; kk < 32; ++kk) {
            float a[TM];
#pragma unroll
            for (int q = 0; q < TM; ++q) a[q] = Xs[ty * TM + q][kk];
            float bv[4];
            *reinterpret_cast<float4*>(bv) = *reinterpret_cast<const float4*>(&Ws[kk][tx * 4]);
#pragma unroll
            for (int q = 0; q < TM; ++q)
#pragma unroll
                for (int r = 0; r < 4; ++r) acc[q][r] += a[q] * bv[r];
        }
        __syncthreads();
    }
#pragma unroll
    for (int q = 0; q < TM; ++q) {
        int c = ty * TM + q;
        *reinterpret_cast<float4*>(
            &Part[(((size_t)b * SK + sk) * rows + c) * NN + n0 + tx * 4]) =
            *reinterpret_cast<float4*>(acc[q]);
    }
}

// ---------------- reduce partials + epilogue ----------------
// mode 0: Out = (X*Wsum - sumPart)*mask
// mode 1: Out -= H*mask*(T0 + X*Wsum - sumPart)
__global__ __launch_bounds__(256) void k_matL_fin(const float* __restrict__ X,
                                                  const float* __restrict__ Part,
                                                  const float* __restrict__ Wsum,
                                                  const float* __restrict__ mask,
                                                  const float* __restrict__ T0,
                                                  float* __restrict__ Out, int rows, int mode) {
    int idx = blockIdx.x * 256 + threadIdx.x;  // over rows*NN/4
    int b = blockIdx.y;
    if (idx >= rows * NN / 4) return;
    int c = idx / (NN / 4);
    int n = (idx % (NN / 4)) * 4;
    float4 s = make_float4(0.f, 0.f, 0.f, 0.f);
#pragma unroll
    for (int sk = 0; sk < SK; ++sk) {
        float4 p = *reinterpret_cast<const float4*>(
            &Part[(((size_t)b * SK + sk) * rows + c) * NN + n]);
        s.x += p.x; s.y += p.y; s.z += p.z; s.w += p.w;
    }
    float4 xv = *reinterpret_cast<const float4*>(&X[((size_t)b * rows + c) * NN + n]);
    float4 wv = *reinterpret_cast<const float4*>(&Wsum[b * NN + n]);
    float4 mv = *reinterpret_cast<const float4*>(&mask[b * NN + n]);
    float y0 = xv.x * wv.x - s.x, y1 = xv.y * wv.y - s.y;
    float y2 = xv.z * wv.z - s.z, y3 = xv.w * wv.w - s.w;
    float4 res;
    if (mode == 0) {
        res = make_float4(y0 * mv.x, y1 * mv.y, y2 * mv.z, y3 * mv.w);
    } else {
        float4 t0 = *reinterpret_cast<const float4*>(&T0[((size_t)b * rows + c) * NN + n]);
        float4 o = *reinterpret_cast<const float4*>(&Out[((size_t)b * rows + c) * NN + n]);
        res = make_float4(o.x - HSTEP * mv.x * (t0.x + y0),
                          o.y - HSTEP * mv.y * (t0.y + y1),
                          o.z - HSTEP * mv.z * (t0.z + y2),
                          o.w - HSTEP * mv.w * (t0.w + y3));
    }
    *reinterpret_cast<float4*>(&Out[((size_t)b * rows + c) * NN + n]) = res;
}

// ---------------- masked row mean per (b,c) ----------------
__global__ __launch_bounds__(256) void k_rowmean(const float* __restrict__ X,
                                                 const float* __restrict__ mask,
                                                 float* __restrict__ meanA, int rows) {
    __shared__ float red[256];
    int c = blockIdx.x, b = blockIdx.y, tid = threadIdx.x;
    const float* src = X + ((size_t)b * rows + c) * NN;
    const float* m = mask + b * NN;
    float s = 0.f, sm = 0.f;
    for (int n = tid; n < NN; n += 256) { float mv = m[n]; s += src[n] * mv; sm += mv; }
    float ts = blockSum(s, red);
    float tm = blockSum(sm, red);
    if (tid == 0) meanA[b * rows + c] = ts / tm;
}

// ---------------- per-column: subtract mean, mask, channel-normalize, relu ----------------
__global__ __launch_bounds__(256) void k_colnorm(float* __restrict__ X,
                                                 const float* __restrict__ mask,
                                                 const float* __restrict__ meanA, int rows) {
    int n = blockIdx.x * 256 + threadIdx.x;
    int b = blockIdx.y;
    float mv = mask[b * NN + n];
    float ss = 0.f;
    for (int c = 0; c < rows; ++c) {
        float v = (X[((size_t)b * rows + c) * NN + n] - meanA[b * rows + c]) * mv;
        ss += v * v;
    }
    float inv = rsqrtf(ss + 0.001f);
    for (int c = 0; c < rows; ++c) {
        float v = (X[((size_t)b * rows + c) * NN + n] - meanA[b * rows + c]) * mv;
        X[((size_t)b * rows + c) * NN + n] = fmaxf(v * inv, 0.f);
    }
}

// ---------------- close: Zout = Kclose @ Z * mask ----------------
__global__ __launch_bounds__(256) void k_close(const float* __restrict__ Zcur,
                                               const float* __restrict__ Kcl,
                                               const float* __restrict__ mask,
                                               float* __restrict__ Zout) {
    int n = blockIdx.x * 256 + threadIdx.x;
    int b = blockIdx.y;
    float acc[COUT] = {};
    for (int c = 0; c < CH; ++c) {
        float zv = Zcur[((size_t)b * CH + c) * NN + n];
#pragma unroll
        for (int o = 0; o < COUT; ++o) acc[o] += Kcl[o * CH + c] * zv;
    }
    float mv = mask[b * NN + n];
#pragma unroll
    for (int o = 0; o < COUT; ++o) Zout[((size_t)b * COUT + o) * NN + n] = acc[o] * mv;
}

// ---------------- center final channels (plain mean) ----------------
__global__ __launch_bounds__(256) void k_center3(const float* __restrict__ Zout, float* __restrict__ Zc3) {
    __shared__ float red[256];
    int c = blockIdx.x, b = blockIdx.y, tid = threadIdx.x;
    const float* src = Zout + ((size_t)b * COUT + c) * NN;
    float s = 0.f;
    for (int n = tid; n < NN; n += 256) s += src[n];
    float mean = blockSum(s, red) / (float)NN;
    float* dst = Zc3 + ((size_t)b * COUT + c) * NN;
    for (int n = tid; n < NN; n += 256) dst[n] = src[n] - mean;
}

__global__ __launch_bounds__(256) void k_n23(const float* __restrict__ Zc3, float* __restrict__ n23) {
    int n = blockIdx.x * 256 + threadIdx.x;
    int g = blockIdx.y, b = blockIdx.z;
    float s = 0.f;
#pragma unroll
    for (int c = 0; c < 3; ++c) { float v = Zc3[((size_t)b * COUT + g * 3 + c) * NN + n]; s += v * v; }
    n23[((size_t)b * 3 + g) * NN + n] = s;
}

// ---------------- final pairwise distances ----------------
__global__ __launch_bounds__(256) void k_dist(const float* __restrict__ Zc3,
                                              const float* __restrict__ n23,
                                              float* __restrict__ dout) {
    __shared__ float Ai[3][64], Aj[3][64], ni[64], nj[64];
    int bg = blockIdx.z;
    int b = bg / 3, g = bg - 3 * b;
    int i0 = blockIdx.x * 64, j0 = blockIdx.y * 64;
    int tid = threadIdx.x;
    if (tid < 64) ni[tid] = n23[((size_t)b * 3 + g) * NN + i0 + tid];
    else if (tid < 128) { int t = tid - 64; nj[t] = n23[((size_t)b * 3 + g) * NN + j0 + t]; }
    for (int e = tid; e < 192; e += 256) {
        int c = e / 64, t = e - c * 64;
        Ai[c][t] = Zc3[((size_t)b * COUT + g * 3 + c) * NN + i0 + t];
    }
    for (int e = tid; e < 192; e += 256) {
        int c = e / 64, t = e - c * 64;
        Aj[c][t] = Zc3[((size_t)b * COUT + g * 3 + c) * NN + j0 + t];
    }
    __syncthreads();
    int tx = tid & 15, ty = tid >> 4;
    for (int q = 0; q < 4; ++q) {
        int i = ty * 4 + q;
        float a0 = Ai[0][i], a1 = Ai[1][i], a2 = Ai[2][i], n2i = ni[i];
        float res[4];
#pragma unroll
        for (int r = 0; r < 4; ++r) {
            int j = tx * 4 + r;
            float D = n2i + nj[j] - 2.f * (a0 * Aj[0][j] + a1 * Aj[1][j] + a2 * Aj[2][j]);
            D = fmaxf(D, 0.f);
            res[r] = (D > 0.f) ? sqrtf(D) : 0.f;
        }
        *reinterpret_cast<float4*>(&dout[(((size_t)b * 3 + g) * NN + i0 + i) * NN + j0 + tx * 4]) =
            *reinterpret_cast<float4*>(res);
    }
}

// ---------------- driver ----------------
extern "C" void kernel_launch(void* const* d_in, const int* in_sizes, int n_in,
                              void* d_out, int out_size, void* d_ws, size_t ws_size,
                              hipStream_t stream) {
    (void)in_sizes; (void)n_in; (void)out_size; (void)ws_size;
    const float* Zin  = (const float*)d_in[0];
    const float* mask = (const float*)d_in[1];
    const float* Kop  = (const float*)d_in[2];
    const float* Kcl  = (const float*)d_in[3];
    const float* Win  = (const float*)d_in[4];
    const float* Bias = (const float*)d_in[5];
    float* out = (float*)d_out;
    float* ws = (float*)d_ws;

    size_t off = 0;
    float* Zcur = ws + off;  off += (size_t)BB * CH * NN;
    float* C0   = ws + off;  off += (size_t)BB * CC * NN;
    float* C1   = ws + off;  off += (size_t)BB * CC * NN;
    float* A1   = ws + off;  off += (size_t)BB * CC * NN;
    float* T0   = ws + off;  off += (size_t)BB * CH * NN;
    float* T1p  = ws + off;  off += (size_t)BB * CH * NN;
    float* Za   = ws + off;  off += (size_t)BB * 65 * NN;
    float* n2g  = ws + off;  off += (size_t)BB * NN;
    float* Wg   = ws + off;  off += (size_t)BB * NN * NN;
    float* Wsum = ws + off;  off += (size_t)BB * NN;
    float* meanA= ws + off;  off += (size_t)BB * CC;
    float* KerC = ws + off;  off += (size_t)NL * 2 * CH * KS * CC;
    float* KerT2= ws + off;  off += (size_t)NL * 2 * CC * KS * CH;
    float* bks  = ws + off;  off += (size_t)NL * 2 * CC * KS;
    float* Zc3  = ws + off;  off += (size_t)BB * COUT * NN;
    float* n23  = ws + off;  off += (size_t)BB * 3 * NN;

    // Split-K partials live in the dists region of d_out (written only at the end).
    float* Part = out;  // needs BB*SK*CC*NN floats = 16.8 MB << 100 MB dists region

    k_prep_w<<<dim3((NL * 2 * CC * CH * KS + 255) / 256), 256, 0, stream>>>(Win, KerC, KerT2);
    k_prep_bks<<<dim3((NL * 2 * CC * KS + 255) / 256), 256, 0, stream>>>(Win, Bias, bks);
    k_open<<<dim3(NN / 256, CH, BB), 256, 0, stream>>>(Zin, mask, Kop, Zcur);
    k_za<<<dim3(65, BB), 256, 0, stream>>>(Zcur, mask, Za);
    k_n2g<<<dim3(NN / 256, BB), 256, 0, stream>>>(Za, n2g);
    k_gramW<<<dim3(16, 16, BB), 256, 0, stream>>>(Za, n2g, mask, Wg);
    k_wsum<<<dim3(NN / 256, BB), 256, 0, stream>>>(Wg, Wsum);

    for (int l = 0; l < NL; ++l) {
        const float* KCl = KerC + (size_t)l * 2 * CH * KS * CC;
        const float* bksl = bks + (size_t)l * 2 * CC * KS;
        const float* KT0 = KerT2 + (size_t)(l * 2 + 0) * CC * KS * CH;
        const float* KT1 = KerT2 + (size_t)(l * 2 + 1) * CC * KS * CH;

        k_conv1f<<<dim3(NN / 128, 8, BB), 256, 0, stream>>>(Zcur, KCl, bksl, mask, C0, C1);
        k_matL_part<4><<<dim3(NN / 32, SK, BB), 256, 0, stream>>>(C1, Wg, Part, CC);
        k_matL_fin<<<dim3(CC * NN / 4 / 256, BB), 256, 0, stream>>>(C1, Part, Wsum, mask, nullptr, A1, CC, 0);
        k_rowmean<<<dim3(CC, BB), 256, 0, stream>>>(C0, mask, meanA, CC);
        k_colnorm<<<dim3(NN / 256, BB), 256, 0, stream>>>(C0, mask, meanA, CC);
        k_rowmean<<<dim3(CC, BB), 256, 0, stream>>>(A1, mask, meanA, CC);
        k_colnorm<<<dim3(NN / 256, BB), 256, 0, stream>>>(A1, mask, meanA, CC);
        k_conv1T<<<dim3(NN / 64, CH / 32, BB), 256, 0, stream>>>(C0, KT0, T0);
        k_conv1T<<<dim3(NN / 64, CH / 32, BB), 256, 0, stream>>>(A1, KT1, T1p);
        k_matL_part<2><<<dim3(NN / 32, SK, BB), 256, 0, stream>>>(T1p, Wg, Part, CH);
        k_matL_fin<<<dim3(CH * NN / 4 / 256, BB), 256, 0, stream>>>(T1p, Part, Wsum, mask, T0, Zcur, CH, 1);
    }

    float* Zout = out + (size_t)BB * 3 * NN * NN;
    k_close<<<dim3(NN / 256, BB), 256, 0, stream>>>(Zcur, Kcl, mask, Zout);
    k_center3<<<dim3(COUT, BB), 256, 0, stream>>>(Zout, Zc3);
    k_n23<<<dim3(NN / 256, 3, BB), 256, 0, stream>>>(Zc3, n23);
    k_dist<<<dim3(16, 16, 3 * BB), 256, 0, stream>>>(Zc3, n23, out);
}